// Round 1
// 828.501 us; speedup vs baseline: 1.0365x; 1.0365x over previous
//
#include <hip/hip_runtime.h>
#include <stdint.h>

typedef unsigned short ushort_t;
typedef float f32x4 __attribute__((ext_vector_type(4)));
typedef _Float16 half8 __attribute__((ext_vector_type(8)));
typedef ushort_t u16x4 __attribute__((ext_vector_type(4)));

#define DEVFN static __device__ __forceinline__

// f32 -> f16 RNE (v_cvt_f16_f32), return raw bits for compact storage
DEVFN ushort_t cvt_f16(float f) {
  union { _Float16 h; ushort_t u; } v;
  v.h = (_Float16)f;
  return v.u;
}

// two f32x4 -> one f16x8 MFMA fragment
DEVFN half8 cvt_frag(f32x4 a, f32x4 b) {
  half8 r;
  r[0] = (_Float16)a[0]; r[1] = (_Float16)a[1];
  r[2] = (_Float16)a[2]; r[3] = (_Float16)a[3];
  r[4] = (_Float16)b[0]; r[5] = (_Float16)b[1];
  r[6] = (_Float16)b[2]; r[7] = (_Float16)b[3];
  return r;
}

// async global->LDS, 16B per lane; lds ptr must be wave-uniform base
DEVFN void gload16(const void* g, void* lds) {
  __builtin_amdgcn_global_load_lds(
      (const __attribute__((address_space(1))) uint32_t*)g,
      (__attribute__((address_space(3))) uint32_t*)lds, 16, 0, 0);
}

// ---------------------------------------------------------------------------
// K0: convert enc [128*49*2048] f32 -> f16, We [512*2048] f32 -> f16
// ---------------------------------------------------------------------------
__global__ __launch_bounds__(256) void k_prep(
    const float* __restrict__ enc, const float* __restrict__ We,
    ushort_t* __restrict__ encf16, ushort_t* __restrict__ Wef16) {
  const int NQ_ENC = 3211264;  // 12845056/4
  const int NQ_TOT = 3473408;  // + 1048576/4
  int idx = blockIdx.x * 256 + threadIdx.x;
  int stride = gridDim.x * 256;
  for (int q = idx; q < NQ_TOT; q += stride) {
    const float* src; ushort_t* dst; int j;
    if (q < NQ_ENC) { src = enc; dst = encf16; j = q; }
    else            { src = We;  dst = Wef16;  j = q - NQ_ENC; }
    f32x4 v = ((const f32x4*)src)[j];
    u16x4 o;
    o[0] = cvt_f16(v[0]); o[1] = cvt_f16(v[1]);
    o[2] = cvt_f16(v[2]); o[3] = cvt_f16(v[3]);
    ((u16x4*)dst)[j] = o;
  }
}

// ---------------------------------------------------------------------------
// K1: att2[b,a] = sum_d dec[b,d]*Wd[a,d] + bd[a]  -> f16  [128][512]
// ---------------------------------------------------------------------------
__global__ __launch_bounds__(256) void k_att2(
    const float* __restrict__ dec, const float* __restrict__ Wd,
    const float* __restrict__ bd, ushort_t* __restrict__ att2) {
  __shared__ __align__(16) float ds[512];
  int b = blockIdx.x, t = threadIdx.x;
  ds[t] = dec[b * 512 + t];
  ds[t + 256] = dec[b * 512 + t + 256];
  __syncthreads();
  for (int o = 0; o < 2; ++o) {
    int a = o * 256 + t;
    const f32x4* wr = (const f32x4*)(Wd + (size_t)a * 512);
    const f32x4* dr = (const f32x4*)ds;
    f32x4 acc = {0.f, 0.f, 0.f, 0.f};
#pragma unroll 8
    for (int k4 = 0; k4 < 128; ++k4) acc += wr[k4] * dr[k4];
    float s = bd[a] + acc[0] + acc[1] + acc[2] + acc[3];
    att2[b * 512 + a] = cvt_f16(s);
  }
}

// ---------------------------------------------------------------------------
// K2: att1 = encf16[6272x2048] @ Wef16[512x2048]^T + be  -> f16 [6272][512]
// all-f16: BM=64, BN=128, BK=64; grid (4, 98) = 392 blocks
// ---------------------------------------------------------------------------
__global__ __launch_bounds__(256) void k_att1(
    const ushort_t* __restrict__ A, const ushort_t* __restrict__ B,
    const float* __restrict__ bias, ushort_t* __restrict__ C) {
  __shared__ __align__(16) ushort_t As[64 * 64];   // 8KB, rows of 8 chunks
  __shared__ __align__(16) ushort_t Bs[128 * 64];  // 16KB
  const int t = threadIdx.x, w = t >> 6, l = t & 63;
  const int wm = w >> 1, wn = w & 1;
  const int m0 = blockIdx.y * 64, n0 = blockIdx.x * 128;
  f32x4 acc[2][4] = {};
  for (int ks = 0; ks < 32; ++ks) {
    const int k0 = ks * 64;
#pragma unroll
    for (int i = 0; i < 2; ++i) {  // A: 512 chunks (64 rows x 8)
      int Lb = i * 256 + (w << 6);
      int L = Lb + l, r = L >> 3, s = L & 7, gc = s ^ (r & 7);
      gload16((const char*)(A + (size_t)(m0 + r) * 2048 + k0) + gc * 16,
              (char*)As + (size_t)Lb * 16);
    }
#pragma unroll
    for (int i = 0; i < 4; ++i) {  // B: 1024 chunks (128 rows x 8)
      int Lb = i * 256 + (w << 6);
      int L = Lb + l, r = L >> 3, s = L & 7, gc = s ^ (r & 7);
      gload16((const char*)(B + (size_t)(n0 + r) * 2048 + k0) + gc * 16,
              (char*)Bs + (size_t)Lb * 16);
    }
    __syncthreads();
    const int q = l >> 4, lm = l & 15;
#pragma unroll
    for (int ksub = 0; ksub < 2; ++ksub) {
      half8 af[2], bfr[4];
#pragma unroll
      for (int mi = 0; mi < 2; ++mi) {
        int r = wm * 32 + mi * 16 + lm;
        int d = ksub * 4 + q;
        af[mi] = *(const half8*)((const char*)As + ((size_t)r * 8 + (d ^ (r & 7))) * 16);
      }
#pragma unroll
      for (int ni = 0; ni < 4; ++ni) {
        int r = wn * 64 + ni * 16 + lm;
        int d = ksub * 4 + q;
        bfr[ni] = *(const half8*)((const char*)Bs + ((size_t)r * 8 + (d ^ (r & 7))) * 16);
      }
#pragma unroll
      for (int mi = 0; mi < 2; ++mi)
#pragma unroll
        for (int ni = 0; ni < 4; ++ni)
          acc[mi][ni] = __builtin_amdgcn_mfma_f32_16x16x32_f16(af[mi], bfr[ni], acc[mi][ni], 0, 0, 0);
    }
    __syncthreads();
  }
  const int q = l >> 4, lm = l & 15;
  for (int mi = 0; mi < 2; ++mi)
    for (int ni = 0; ni < 4; ++ni)
      for (int rg = 0; rg < 4; ++rg) {
        int m = m0 + wm * 32 + mi * 16 + q * 4 + rg;
        int n = n0 + wn * 64 + ni * 16 + lm;
        C[(size_t)m * 512 + n] = cvt_f16(acc[mi][ni][rg] + bias[n]);
      }
}

// ---------------------------------------------------------------------------
// K3: u[b, n=k*512+i] = sum_j att2[b,j] * Wb[n,j]   (Wb flat [262144][512])
// M=128(all b), N-tile=128, BK=64. A f16 (8 chunks/row), B f32 (16 chunks/row)
// ---------------------------------------------------------------------------
__global__ __launch_bounds__(256) void k_u(
    const ushort_t* __restrict__ att2, const float* __restrict__ Wb,
    ushort_t* __restrict__ u) {
  __shared__ __align__(16) ushort_t As[128 * 64];  // 16KB f16
  __shared__ __align__(16) float Bs[128 * 64];     // 32KB f32
  const int t = threadIdx.x, w = t >> 6, l = t & 63;
  const int wm = w >> 1, wn = w & 1;
  const int n0 = blockIdx.x * 128;
  f32x4 acc[4][4] = {};
  for (int ks = 0; ks < 8; ++ks) {
    const int j0 = ks * 64;
#pragma unroll
    for (int i = 0; i < 4; ++i) {  // A: 1024 chunks (128 rows x 8)
      int Lb = i * 256 + (w << 6);
      int L = Lb + l, r = L >> 3, s = L & 7, gc = s ^ (r & 7);
      gload16((const char*)(att2 + (size_t)r * 512 + j0) + gc * 16,
              (char*)As + (size_t)Lb * 16);
    }
#pragma unroll
    for (int i = 0; i < 8; ++i) {  // B: 2048 chunks (128 rows x 16)
      int Lb = i * 256 + (w << 6);
      int L = Lb + l, r = L >> 4, s = L & 15, gc = s ^ (r & 15);
      gload16((const char*)(Wb + (size_t)(n0 + r) * 512 + j0) + gc * 16,
              (char*)Bs + (size_t)Lb * 16);
    }
    __syncthreads();
    const int q = l >> 4, lm = l & 15;
#pragma unroll
    for (int ksub = 0; ksub < 2; ++ksub) {
      half8 af[4], bfr[4];
#pragma unroll
      for (int mi = 0; mi < 4; ++mi) {
        int r = wm * 64 + mi * 16 + lm;
        int d = ksub * 4 + q;
        af[mi] = *(const half8*)((const char*)As + ((size_t)r * 8 + (d ^ (r & 7))) * 16);
      }
#pragma unroll
      for (int ni = 0; ni < 4; ++ni) {
        int r = wn * 64 + ni * 16 + lm;
        int d0 = ksub * 8 + q * 2;
        f32x4 v0 = *(const f32x4*)((const char*)Bs + ((size_t)r * 16 + (d0 ^ (r & 15))) * 16);
        f32x4 v1 = *(const f32x4*)((const char*)Bs + ((size_t)r * 16 + ((d0 + 1) ^ (r & 15))) * 16);
        bfr[ni] = cvt_frag(v0, v1);
      }
#pragma unroll
      for (int mi = 0; mi < 4; ++mi)
#pragma unroll
        for (int ni = 0; ni < 4; ++ni)
          acc[mi][ni] = __builtin_amdgcn_mfma_f32_16x16x32_f16(af[mi], bfr[ni], acc[mi][ni], 0, 0, 0);
    }
    __syncthreads();
  }
  const int q = l >> 4, lm = l & 15;
  for (int mi = 0; mi < 4; ++mi)
    for (int ni = 0; ni < 4; ++ni)
      for (int rg = 0; rg < 4; ++rg) {
        int b = wm * 64 + mi * 16 + q * 4 + rg;
        int n = n0 + wn * 64 + ni * 16 + lm;
        u[(size_t)b * 262144 + n] = cvt_f16(acc[mi][ni][rg]);
      }
}

// ---------------------------------------------------------------------------
// K4: per (b, k-quarter): bil[p,k] = sum_i att1[b,p,i]*u[b,k,i];
//     att[b,p] += sum_k relu(bil+bb[k])*Wf[k]   (atomicAdd)
// M=64 (p, pad 49->64), N=128 (k), K=512 (i); all f16
// ---------------------------------------------------------------------------
__global__ __launch_bounds__(256) void k_bil(
    const ushort_t* __restrict__ att1, const ushort_t* __restrict__ u,
    const float* __restrict__ bb, const float* __restrict__ Wf,
    float* __restrict__ att) {
  __shared__ __align__(16) ushort_t As[64 * 64];   // 8KB
  __shared__ __align__(16) ushort_t Bs[128 * 64];  // 16KB
  const int t = threadIdx.x, w = t >> 6, l = t & 63;
  const int wm = w >> 1, wn = w & 1;
  const int b = blockIdx.x, kq = blockIdx.y;
  const ushort_t* Arow = att1 + (size_t)b * 49 * 512;
  const ushort_t* Brow = u + (size_t)b * 262144 + (size_t)kq * 128 * 512;
  f32x4 acc[2][4] = {};
  for (int ks = 0; ks < 8; ++ks) {
    const int i0 = ks * 64;
#pragma unroll
    for (int i = 0; i < 2; ++i) {  // A: 512 chunks (64 rows x 8)
      int Lb = i * 256 + (w << 6);
      int L = Lb + l, r = L >> 3, s = L & 7, gc = s ^ (r & 7);
      gload16((const char*)(Arow + (size_t)r * 512 + i0) + gc * 16,
              (char*)As + (size_t)Lb * 16);
    }
#pragma unroll
    for (int i = 0; i < 4; ++i) {  // B: 1024 chunks (128 rows x 8)
      int Lb = i * 256 + (w << 6);
      int L = Lb + l, r = L >> 3, s = L & 7, gc = s ^ (r & 7);
      gload16((const char*)(Brow + (size_t)r * 512 + i0) + gc * 16,
              (char*)Bs + (size_t)Lb * 16);
    }
    __syncthreads();
    const int q = l >> 4, lm = l & 15;
#pragma unroll
    for (int ksub = 0; ksub < 2; ++ksub) {
      half8 af[2], bfr[4];
#pragma unroll
      for (int mi = 0; mi < 2; ++mi) {
        int r = wm * 32 + mi * 16 + lm;
        int d = ksub * 4 + q;
        af[mi] = *(const half8*)((const char*)As + ((size_t)r * 8 + (d ^ (r & 7))) * 16);
      }
#pragma unroll
      for (int ni = 0; ni < 4; ++ni) {
        int r = wn * 64 + ni * 16 + lm;
        int d = ksub * 4 + q;
        bfr[ni] = *(const half8*)((const char*)Bs + ((size_t)r * 8 + (d ^ (r & 7))) * 16);
      }
#pragma unroll
      for (int mi = 0; mi < 2; ++mi)
#pragma unroll
        for (int ni = 0; ni < 4; ++ni)
          acc[mi][ni] = __builtin_amdgcn_mfma_f32_16x16x32_f16(af[mi], bfr[ni], acc[mi][ni], 0, 0, 0);
    }
    __syncthreads();
  }
  const int q = l >> 4, lm = l & 15;
#pragma unroll
  for (int mi = 0; mi < 2; ++mi) {
#pragma unroll
    for (int rg = 0; rg < 4; ++rg) {
      float s = 0.f;
#pragma unroll
      for (int ni = 0; ni < 4; ++ni) {
        int k = kq * 128 + wn * 64 + ni * 16 + lm;
        float v = acc[mi][ni][rg] + bb[k];
        s += fmaxf(v, 0.f) * Wf[k];
      }
      s += __shfl_xor(s, 1);
      s += __shfl_xor(s, 2);
      s += __shfl_xor(s, 4);
      s += __shfl_xor(s, 8);
      int p = wm * 32 + mi * 16 + q * 4 + rg;
      if (lm == 0 && p < 49) atomicAdd(att + b * 49 + p, s);
    }
  }
}

// ---------------------------------------------------------------------------
// K5: fused softmax + awe: wave 0 computes softmax over P=49 (redundant per
// h-block; h==0 writes alpha); then awe[b,e] = sum_p alpha[b,p]*enc[b,p,e]
// ---------------------------------------------------------------------------
__global__ __launch_bounds__(256) void k_awe(
    const float* __restrict__ enc, const float* __restrict__ att,
    float* __restrict__ awe, float* __restrict__ alpha) {
  __shared__ float al[49];
  int b = blockIdx.y, h = blockIdx.x, t = threadIdx.x;
  if (t < 64) {
    float x = (t < 49) ? att[b * 49 + t] : -1e30f;
    float m = x;
    for (int off = 32; off; off >>= 1) m = fmaxf(m, __shfl_xor(m, off));
    float e = (t < 49) ? __expf(x - m) : 0.f;
    float s = e;
    for (int off = 32; off; off >>= 1) s += __shfl_xor(s, off);
    if (t < 49) {
      float a = e / s;
      al[t] = a;
      if (h == 0) alpha[b * 49 + t] = a;
    }
  }
  __syncthreads();
  int e4 = h * 256 + t;  // 0..511
  const f32x4* ep = (const f32x4*)(enc + (size_t)b * 49 * 2048) + e4;
  f32x4 acc = {0.f, 0.f, 0.f, 0.f};
#pragma unroll 7
  for (int p = 0; p < 49; ++p) acc += al[p] * ep[(size_t)p * 512];
  ((f32x4*)(awe + (size_t)b * 2048))[e4] = acc;
}

// ---------------------------------------------------------------------------
extern "C" void kernel_launch(void* const* d_in, const int* in_sizes, int n_in,
                              void* d_out, int out_size, void* d_ws, size_t ws_size,
                              hipStream_t stream) {
  (void)in_sizes; (void)n_in; (void)out_size; (void)ws_size;
  const float* enc = (const float*)d_in[0];
  const float* dec = (const float*)d_in[1];
  const float* We  = (const float*)d_in[2];
  const float* be  = (const float*)d_in[3];
  const float* Wd  = (const float*)d_in[4];
  const float* bd  = (const float*)d_in[5];
  const float* Wb  = (const float*)d_in[6];
  const float* bb  = (const float*)d_in[7];
  const float* Wf  = (const float*)d_in[8];
  // d_in[9] = bf[0]: softmax-shift-invariant, intentionally unused.

  char* ws = (char*)d_ws;
  ushort_t* att2   = (ushort_t*)ws;                   // 128*512*2      = 131072 B
  ushort_t* att1   = (ushort_t*)(ws + 131072);        // 6336*512*2    = 6488064 B
  ushort_t* u      = (ushort_t*)(ws + 6619136);       // 128*262144*2  = 67108864 B
  float*    att    = (float*)(ws + 73728000);         // 128*49*4      = 25088 B
  ushort_t* encf16 = (ushort_t*)(ws + 73753088);      // 12845056*2    = 25690112 B
  ushort_t* Wef16  = (ushort_t*)(ws + 99443200);      // 1048576*2     = 2097152 B
  // total ws used: 101540352 B

  float* awe   = (float*)d_out;            // [128][2048]
  float* alpha = (float*)d_out + 262144;   // [128][49]

  hipMemsetAsync(att, 0, 128 * 49 * sizeof(float), stream);
  k_prep<<<dim3(2048), 256, 0, stream>>>(enc, We, encf16, Wef16);
  k_att2<<<dim3(128), 256, 0, stream>>>(dec, Wd, bd, att2);
  k_att1<<<dim3(4, 98), 256, 0, stream>>>(encf16, Wef16, be, att1);
  k_u<<<dim3(2048), 256, 0, stream>>>(att2, Wb, u);
  k_bil<<<dim3(128, 4), 256, 0, stream>>>(att1, u, bb, Wf, att);
  k_awe<<<dim3(2, 128), 256, 0, stream>>>(enc, att, awe, alpha);
}

// Round 2
// 799.067 us; speedup vs baseline: 1.0747x; 1.0368x over previous
//
#include <hip/hip_runtime.h>
#include <stdint.h>

typedef unsigned short ushort_t;
typedef float f32x4 __attribute__((ext_vector_type(4)));
typedef _Float16 half8 __attribute__((ext_vector_type(8)));
typedef ushort_t u16x4 __attribute__((ext_vector_type(4)));

#define DEVFN static __device__ __forceinline__

// f32 -> f16 RNE (v_cvt_f16_f32), return raw bits for compact storage
DEVFN ushort_t cvt_f16(float f) {
  union { _Float16 h; ushort_t u; } v;
  v.h = (_Float16)f;
  return v.u;
}

// two f32x4 -> one f16x8 MFMA fragment
DEVFN half8 cvt_frag(f32x4 a, f32x4 b) {
  half8 r;
  r[0] = (_Float16)a[0]; r[1] = (_Float16)a[1];
  r[2] = (_Float16)a[2]; r[3] = (_Float16)a[3];
  r[4] = (_Float16)b[0]; r[5] = (_Float16)b[1];
  r[6] = (_Float16)b[2]; r[7] = (_Float16)b[3];
  return r;
}

// async global->LDS, 16B per lane; lds ptr must be wave-uniform base
DEVFN void gload16(const void* g, void* lds) {
  __builtin_amdgcn_global_load_lds(
      (const __attribute__((address_space(1))) uint32_t*)g,
      (__attribute__((address_space(3))) uint32_t*)lds, 16, 0, 0);
}

// ---------------------------------------------------------------------------
// K_PRE: fused independent prologue work, branch on blockIdx.x
//   blocks [0,128):   att2[b,a] = dec[b,:]·Wd[a,:] + bd[a] -> f16
//   block  128:       zero att accumulator (128*49 floats)
//   blocks [129,2177): convert enc (12.8M f32) and We (1M f32) -> f16
// ---------------------------------------------------------------------------
__global__ __launch_bounds__(256) void k_pre(
    const float* __restrict__ enc, const float* __restrict__ We,
    const float* __restrict__ dec, const float* __restrict__ Wd,
    const float* __restrict__ bd,
    ushort_t* __restrict__ encf16, ushort_t* __restrict__ Wef16,
    ushort_t* __restrict__ att2, float* __restrict__ att) {
  __shared__ __align__(16) float ds[512];
  const int bid = blockIdx.x, t = threadIdx.x;
  if (bid < 128) {
    // --- att2 ---
    int b = bid;
    ds[t] = dec[b * 512 + t];
    ds[t + 256] = dec[b * 512 + t + 256];
    __syncthreads();
    for (int o = 0; o < 2; ++o) {
      int a = o * 256 + t;
      const f32x4* wr = (const f32x4*)(Wd + (size_t)a * 512);
      const f32x4* dr = (const f32x4*)ds;
      f32x4 acc = {0.f, 0.f, 0.f, 0.f};
#pragma unroll 8
      for (int k4 = 0; k4 < 128; ++k4) acc += wr[k4] * dr[k4];
      float s = bd[a] + acc[0] + acc[1] + acc[2] + acc[3];
      att2[b * 512 + a] = cvt_f16(s);
    }
  } else if (bid == 128) {
    // --- zero att ---
    for (int i = t; i < 128 * 49; i += 256) att[i] = 0.f;
  } else {
    // --- f32 -> f16 conversion ---
    const int NQ_ENC = 3211264;  // 12845056/4
    const int NQ_TOT = 3473408;  // + 1048576/4
    int idx = (bid - 129) * 256 + t;
    const int stride = 2048 * 256;
    for (int q = idx; q < NQ_TOT; q += stride) {
      const float* src; ushort_t* dst; int j;
      if (q < NQ_ENC) { src = enc; dst = encf16; j = q; }
      else            { src = We;  dst = Wef16;  j = q - NQ_ENC; }
      f32x4 v = ((const f32x4*)src)[j];
      u16x4 o;
      o[0] = cvt_f16(v[0]); o[1] = cvt_f16(v[1]);
      o[2] = cvt_f16(v[2]); o[3] = cvt_f16(v[3]);
      ((u16x4*)dst)[j] = o;
    }
  }
}

// ---------------------------------------------------------------------------
// K_MM1: fused independent GEMMs, branch on blockIdx.x (shared 48KB LDS pool)
//   blocks [0,392):    att1 = encf16[6272x2048] @ Wef16[512x2048]^T + be -> f16
//                      BM=64, BN=128, BK=64; block = (m-tile my, n-tile nx)
//   blocks [392,2440): u[b,n] = sum_j att2[b,j]*Wb[n,j]; M=128, BN=128, BK=64
// att1 blocks dispatched first (long serial K-loop) so u's HBM stream hides them.
// ---------------------------------------------------------------------------
__global__ __launch_bounds__(256) void k_mm1(
    const ushort_t* __restrict__ Ae, const ushort_t* __restrict__ Be,
    const float* __restrict__ be,
    const ushort_t* __restrict__ att2, const float* __restrict__ Wb,
    ushort_t* __restrict__ att1, ushort_t* __restrict__ u) {
  __shared__ __align__(16) char smem[49152];
  const int bid = blockIdx.x;
  const int t = threadIdx.x, w = t >> 6, l = t & 63;
  const int wm = w >> 1, wn = w & 1;
  const int q = l >> 4, lm = l & 15;

  if (bid < 392) {
    // ---------------- att1 branch ----------------
    ushort_t* As = (ushort_t*)smem;            // 8KB  (64 rows x 8 chunks)
    ushort_t* Bs = (ushort_t*)(smem + 8192);   // 16KB (128 rows x 8 chunks)
    const int m0 = (bid >> 2) * 64, n0 = (bid & 3) * 128;
    f32x4 acc[2][4] = {};
    for (int ks = 0; ks < 32; ++ks) {
      const int k0 = ks * 64;
#pragma unroll
      for (int i = 0; i < 2; ++i) {  // A: 512 chunks
        int Lb = i * 256 + (w << 6);
        int L = Lb + l, r = L >> 3, s = L & 7, gc = s ^ (r & 7);
        gload16((const char*)(Ae + (size_t)(m0 + r) * 2048 + k0) + gc * 16,
                (char*)As + (size_t)Lb * 16);
      }
#pragma unroll
      for (int i = 0; i < 4; ++i) {  // B: 1024 chunks
        int Lb = i * 256 + (w << 6);
        int L = Lb + l, r = L >> 3, s = L & 7, gc = s ^ (r & 7);
        gload16((const char*)(Be + (size_t)(n0 + r) * 2048 + k0) + gc * 16,
                (char*)Bs + (size_t)Lb * 16);
      }
      __syncthreads();
#pragma unroll
      for (int ksub = 0; ksub < 2; ++ksub) {
        half8 af[2], bfr[4];
#pragma unroll
        for (int mi = 0; mi < 2; ++mi) {
          int r = wm * 32 + mi * 16 + lm;
          int d = ksub * 4 + q;
          af[mi] = *(const half8*)((const char*)As + ((size_t)r * 8 + (d ^ (r & 7))) * 16);
        }
#pragma unroll
        for (int ni = 0; ni < 4; ++ni) {
          int r = wn * 64 + ni * 16 + lm;
          int d = ksub * 4 + q;
          bfr[ni] = *(const half8*)((const char*)Bs + ((size_t)r * 8 + (d ^ (r & 7))) * 16);
        }
#pragma unroll
        for (int mi = 0; mi < 2; ++mi)
#pragma unroll
          for (int ni = 0; ni < 4; ++ni)
            acc[mi][ni] = __builtin_amdgcn_mfma_f32_16x16x32_f16(af[mi], bfr[ni], acc[mi][ni], 0, 0, 0);
      }
      __syncthreads();
    }
    for (int mi = 0; mi < 2; ++mi)
      for (int ni = 0; ni < 4; ++ni)
        for (int rg = 0; rg < 4; ++rg) {
          int m = m0 + wm * 32 + mi * 16 + q * 4 + rg;
          int n = n0 + wn * 64 + ni * 16 + lm;
          att1[(size_t)m * 512 + n] = cvt_f16(acc[mi][ni][rg] + be[n]);
        }
  } else {
    // ---------------- u branch ----------------
    ushort_t* As = (ushort_t*)smem;          // 16KB f16 (128 rows x 8 chunks)
    float*    Bs = (float*)(smem + 16384);   // 32KB f32 (128 rows x 16 chunks)
    const int n0 = (bid - 392) * 128;
    f32x4 acc[4][4] = {};
    for (int ks = 0; ks < 8; ++ks) {
      const int j0 = ks * 64;
#pragma unroll
      for (int i = 0; i < 4; ++i) {  // A: 1024 chunks
        int Lb = i * 256 + (w << 6);
        int L = Lb + l, r = L >> 3, s = L & 7, gc = s ^ (r & 7);
        gload16((const char*)(att2 + (size_t)r * 512 + j0) + gc * 16,
                (char*)As + (size_t)Lb * 16);
      }
#pragma unroll
      for (int i = 0; i < 8; ++i) {  // B: 2048 chunks
        int Lb = i * 256 + (w << 6);
        int L = Lb + l, r = L >> 4, s = L & 15, gc = s ^ (r & 15);
        gload16((const char*)(Wb + (size_t)(n0 + r) * 512 + j0) + gc * 16,
                (char*)Bs + (size_t)Lb * 16);
      }
      __syncthreads();
#pragma unroll
      for (int ksub = 0; ksub < 2; ++ksub) {
        half8 af[4], bfr[4];
#pragma unroll
        for (int mi = 0; mi < 4; ++mi) {
          int r = wm * 64 + mi * 16 + lm;
          int d = ksub * 4 + q;
          af[mi] = *(const half8*)((const char*)As + ((size_t)r * 8 + (d ^ (r & 7))) * 16);
        }
#pragma unroll
        for (int ni = 0; ni < 4; ++ni) {
          int r = wn * 64 + ni * 16 + lm;
          int d0 = ksub * 8 + q * 2;
          f32x4 v0 = *(const f32x4*)((const char*)Bs + ((size_t)r * 16 + (d0 ^ (r & 15))) * 16);
          f32x4 v1 = *(const f32x4*)((const char*)Bs + ((size_t)r * 16 + ((d0 + 1) ^ (r & 15))) * 16);
          bfr[ni] = cvt_frag(v0, v1);
        }
#pragma unroll
        for (int mi = 0; mi < 4; ++mi)
#pragma unroll
          for (int ni = 0; ni < 4; ++ni)
            acc[mi][ni] = __builtin_amdgcn_mfma_f32_16x16x32_f16(af[mi], bfr[ni], acc[mi][ni], 0, 0, 0);
      }
      __syncthreads();
    }
    for (int mi = 0; mi < 4; ++mi)
      for (int ni = 0; ni < 4; ++ni)
        for (int rg = 0; rg < 4; ++rg) {
          int b = wm * 64 + mi * 16 + q * 4 + rg;
          int n = n0 + wn * 64 + ni * 16 + lm;
          u[(size_t)b * 262144 + n] = cvt_f16(acc[mi][ni][rg]);
        }
  }
}

// ---------------------------------------------------------------------------
// K_BIL: per (b, k-quarter): bil[p,k] = sum_i att1[b,p,i]*u[b,k,i];
//     att[b,p] += sum_k relu(bil+bb[k])*Wf[k]   (atomicAdd)
// M=64 (p, pad 49->64), N=128 (k), K=512 (i); all f16
// ---------------------------------------------------------------------------
__global__ __launch_bounds__(256) void k_bil(
    const ushort_t* __restrict__ att1, const ushort_t* __restrict__ u,
    const float* __restrict__ bb, const float* __restrict__ Wf,
    float* __restrict__ att) {
  __shared__ __align__(16) ushort_t As[64 * 64];   // 8KB
  __shared__ __align__(16) ushort_t Bs[128 * 64];  // 16KB
  const int t = threadIdx.x, w = t >> 6, l = t & 63;
  const int wm = w >> 1, wn = w & 1;
  const int b = blockIdx.x, kq = blockIdx.y;
  const ushort_t* Arow = att1 + (size_t)b * 49 * 512;
  const ushort_t* Brow = u + (size_t)b * 262144 + (size_t)kq * 128 * 512;
  f32x4 acc[2][4] = {};
  for (int ks = 0; ks < 8; ++ks) {
    const int i0 = ks * 64;
#pragma unroll
    for (int i = 0; i < 2; ++i) {  // A: 512 chunks (64 rows x 8)
      int Lb = i * 256 + (w << 6);
      int L = Lb + l, r = L >> 3, s = L & 7, gc = s ^ (r & 7);
      gload16((const char*)(Arow + (size_t)r * 512 + i0) + gc * 16,
              (char*)As + (size_t)Lb * 16);
    }
#pragma unroll
    for (int i = 0; i < 4; ++i) {  // B: 1024 chunks (128 rows x 8)
      int Lb = i * 256 + (w << 6);
      int L = Lb + l, r = L >> 3, s = L & 7, gc = s ^ (r & 7);
      gload16((const char*)(Brow + (size_t)r * 512 + i0) + gc * 16,
              (char*)Bs + (size_t)Lb * 16);
    }
    __syncthreads();
    const int q = l >> 4, lm = l & 15;
#pragma unroll
    for (int ksub = 0; ksub < 2; ++ksub) {
      half8 af[2], bfr[4];
#pragma unroll
      for (int mi = 0; mi < 2; ++mi) {
        int r = wm * 32 + mi * 16 + lm;
        int d = ksub * 4 + q;
        af[mi] = *(const half8*)((const char*)As + ((size_t)r * 8 + (d ^ (r & 7))) * 16);
      }
#pragma unroll
      for (int ni = 0; ni < 4; ++ni) {
        int r = wn * 64 + ni * 16 + lm;
        int d = ksub * 4 + q;
        bfr[ni] = *(const half8*)((const char*)Bs + ((size_t)r * 8 + (d ^ (r & 7))) * 16);
      }
#pragma unroll
      for (int mi = 0; mi < 2; ++mi)
#pragma unroll
        for (int ni = 0; ni < 4; ++ni)
          acc[mi][ni] = __builtin_amdgcn_mfma_f32_16x16x32_f16(af[mi], bfr[ni], acc[mi][ni], 0, 0, 0);
    }
    __syncthreads();
  }
  const int q = l >> 4, lm = l & 15;
#pragma unroll
  for (int mi = 0; mi < 2; ++mi) {
#pragma unroll
    for (int rg = 0; rg < 4; ++rg) {
      float s = 0.f;
#pragma unroll
      for (int ni = 0; ni < 4; ++ni) {
        int k = kq * 128 + wn * 64 + ni * 16 + lm;
        float v = acc[mi][ni][rg] + bb[k];
        s += fmaxf(v, 0.f) * Wf[k];
      }
      s += __shfl_xor(s, 1);
      s += __shfl_xor(s, 2);
      s += __shfl_xor(s, 4);
      s += __shfl_xor(s, 8);
      int p = wm * 32 + mi * 16 + q * 4 + rg;
      if (lm == 0 && p < 49) atomicAdd(att + b * 49 + p, s);
    }
  }
}

// ---------------------------------------------------------------------------
// K_AWE: fused softmax + awe: wave 0 computes softmax over P=49 (redundant per
// h-block; h==0 writes alpha); then awe[b,e] = sum_p alpha[b,p]*enc[b,p,e]
// ---------------------------------------------------------------------------
__global__ __launch_bounds__(256) void k_awe(
    const float* __restrict__ enc, const float* __restrict__ att,
    float* __restrict__ awe, float* __restrict__ alpha) {
  __shared__ float al[49];
  int b = blockIdx.y, h = blockIdx.x, t = threadIdx.x;
  if (t < 64) {
    float x = (t < 49) ? att[b * 49 + t] : -1e30f;
    float m = x;
    for (int off = 32; off; off >>= 1) m = fmaxf(m, __shfl_xor(m, off));
    float e = (t < 49) ? __expf(x - m) : 0.f;
    float s = e;
    for (int off = 32; off; off >>= 1) s += __shfl_xor(s, off);
    if (t < 49) {
      float a = e / s;
      al[t] = a;
      if (h == 0) alpha[b * 49 + t] = a;
    }
  }
  __syncthreads();
  int e4 = h * 256 + t;  // 0..511
  const f32x4* ep = (const f32x4*)(enc + (size_t)b * 49 * 2048) + e4;
  f32x4 acc = {0.f, 0.f, 0.f, 0.f};
#pragma unroll 7
  for (int p = 0; p < 49; ++p) acc += al[p] * ep[(size_t)p * 512];
  ((f32x4*)(awe + (size_t)b * 2048))[e4] = acc;
}

// ---------------------------------------------------------------------------
extern "C" void kernel_launch(void* const* d_in, const int* in_sizes, int n_in,
                              void* d_out, int out_size, void* d_ws, size_t ws_size,
                              hipStream_t stream) {
  (void)in_sizes; (void)n_in; (void)out_size; (void)ws_size;
  const float* enc = (const float*)d_in[0];
  const float* dec = (const float*)d_in[1];
  const float* We  = (const float*)d_in[2];
  const float* be  = (const float*)d_in[3];
  const float* Wd  = (const float*)d_in[4];
  const float* bd  = (const float*)d_in[5];
  const float* Wb  = (const float*)d_in[6];
  const float* bb  = (const float*)d_in[7];
  const float* Wf  = (const float*)d_in[8];
  // d_in[9] = bf[0]: softmax-shift-invariant, intentionally unused.

  char* ws = (char*)d_ws;
  ushort_t* att2   = (ushort_t*)ws;                   // 128*512*2      = 131072 B
  ushort_t* att1   = (ushort_t*)(ws + 131072);        // 6336*512*2    = 6488064 B
  ushort_t* u      = (ushort_t*)(ws + 6619136);       // 128*262144*2  = 67108864 B
  float*    att    = (float*)(ws + 73728000);         // 128*49*4      = 25088 B
  ushort_t* encf16 = (ushort_t*)(ws + 73753088);      // 12845056*2    = 25690112 B
  ushort_t* Wef16  = (ushort_t*)(ws + 99443200);      // 1048576*2     = 2097152 B
  // total ws used: 101540352 B

  float* awe   = (float*)d_out;            // [128][2048]
  float* alpha = (float*)d_out + 262144;   // [128][49]

  k_pre<<<dim3(2177), 256, 0, stream>>>(enc, We, dec, Wd, bd, encf16, Wef16, att2, att);
  k_mm1<<<dim3(2440), 256, 0, stream>>>(encf16, Wef16, be, att2, Wb, att1, u);
  k_bil<<<dim3(128, 4), 256, 0, stream>>>(att1, u, bb, Wf, att);
  k_awe<<<dim3(2, 128), 256, 0, stream>>>(enc, att, awe, alpha);
}